// Round 11
// baseline (432.898 us; speedup 1.0000x reference)
//
#include <hip/hip_runtime.h>

#define NB 4
#define NT 8192
#define NC 64
#define NS 256
#define NV 256
#define NL 30

typedef __attribute__((ext_vector_type(8))) short bf16x8;
typedef __attribute__((ext_vector_type(4))) float f32x4;
typedef unsigned short ushort_t;

#define MFMA(a, b, c) __builtin_amdgcn_mfma_f32_16x16x32_bf16(a, b, c, 0, 0, 0)

// weight arena (bf16 elems)
#define OFF_WCAT 0
#define SZ_WCAT  (NL * 16384)            // swizzled [l][kk=4][n=128][j=32]
#define OFF_RW   (OFF_WCAT + SZ_WCAT)
#define SZ_RW    (NL * 4096)             // swizzled [l][kk=2][n=64][j=32]
#define OFF_SWG  (OFF_RW + SZ_RW)
#define SZ_SWG   (6 * 81920)             // [kkall=60][n=256][j=32] (6 groups x 10)
#define OFF_W0   (OFF_SWG + SZ_SWG)      // [kk=8][n=256][j=32]
#define OFF_W1   (OFF_W0 + 65536)        // [kk=8][n=256][j=32]
#define TOTAL_W  (OFF_W1 + 65536)        // 1,236,992 elems (2.42 MB)
#define N_PREP   (TOTAL_W + 1792)        // + sbg[6][256] + sbtot[256] fp32

#define X_ELEMS  (NB * NT * NC)          // 2,097,152 (4 MB bf16)
#define SK_ELEMS (NB * NT * NS)          // 8,388,608 (16 MB bf16)
#define G_ELEMS  (NB * NT * NC)          // gate slot (4 MB bf16)

// small path (round-3 proven): 5 shared gate slots + skip buffer
#define WS_SMALL ((size_t)(2 * X_ELEMS + SK_ELEMS + 5 * G_ELEMS + TOTAL_W) * 2 \
                  + 1792 * 4)
// big path: 30 gate slots, no skip buffer
#define WS_BIG   ((size_t)(2 * X_ELEMS + 30 * G_ELEMS + TOTAL_W) * 2 + 1792 * 4)

__device__ inline ushort_t f2bu(float f) {
  union { float f; unsigned u; } v; v.f = f;
  unsigned r = v.u + 0x7FFFu + ((v.u >> 16) & 1u);
  return (ushort_t)(r >> 16);
}
__device__ inline float b2f(ushort_t h) {
  union { unsigned u; float f; } v; v.u = ((unsigned)h) << 16; return v.f;
}

__global__ void sentinel_kernel(float* __restrict__ out) {
  if (threadIdx.x == 0) out[0] = -1234.0f;
}

// ---------------------------------------------------------------------------
// prep: weight swizzle + bias sums + out[0]=0 (zero_kernel folded in).
// ---------------------------------------------------------------------------
__global__ __launch_bounds__(256) void prep_kernel(
    const float* __restrict__ cw, const float* __restrict__ rw,
    const float* __restrict__ sw, const float* __restrict__ w0,
    const float* __restrict__ w1, const float* __restrict__ sb_all,
    ushort_t* __restrict__ wt, float* __restrict__ sbg,
    float* __restrict__ out0)
{
  int idx = blockIdx.x * 256 + threadIdx.x;
  if (idx == 0) out0[0] = 0.f;
  if (idx >= N_PREP) return;
  if (idx >= TOTAL_W) {
    int j = idx - TOTAL_W;
    if (j < 1536) {
      int g = j >> 8, n = j & 255;
      float s = 0.f;
#pragma unroll
      for (int jj = 0; jj < 5; ++jj) s += sb_all[(5 * g + jj) * 256 + n];
      sbg[j] = s;
    } else {
      int n = j - 1536;
      float s = 0.f;
      for (int jj = 0; jj < NL; ++jj) s += sb_all[jj * 256 + n];
      sbg[j] = s;                         // total bias over all 30 layers
    }
    return;
  }
  float v;
  if (idx < OFF_RW) {
    int e = idx; int l = e >> 14; int r = e & 16383;
    int kk = r >> 12, n = (r >> 5) & 127, j = r & 31;
    int k = kk * 32 + j, tap = k >> 6, c = k & 63;
    v = cw[(((l * 2 + tap) << 6) + c) * 128 + n];
  } else if (idx < OFF_SWG) {
    int e = idx - OFF_RW; int l = e >> 12; int r = e & 4095;
    int kk = r >> 11, n = (r >> 5) & 63, j = r & 31;
    int k = kk * 32 + j;
    v = rw[((l << 6) + k) * 64 + n];
  } else if (idx < OFF_W0) {
    int e = idx - OFF_SWG; int g = e / 81920; int r = e % 81920;
    int kk = r >> 13; int rem = r & 8191;
    int n = rem >> 5, jj = rem & 31;
    int k = kk * 32 + jj;                       // 0..319
    v = sw[(size_t)(320 * g + k) * 256 + n];
  } else if (idx < OFF_W1) {
    int e = idx - OFF_W0;
    int kk = e >> 13; int rem = e & 8191;
    int n = rem >> 5, jj = rem & 31;
    int k = kk * 32 + jj;
    v = w0[k * 256 + n];
  } else {
    int e = idx - OFF_W1;
    int kk = e >> 13; int rem = e & 8191;
    int n = rem >> 5, jj = rem & 31;
    int k = kk * 32 + jj;
    v = w1[k * 256 + n];
  }
  wt[idx] = f2bu(v);
}

// ---------------------------------------------------------------------------
// embed: FALLBACK path only (big path fuses embedding into chain5 blk0).
// ---------------------------------------------------------------------------
__global__ __launch_bounds__(256) void embed_kernel(
    const int* __restrict__ wf, const float* __restrict__ embed,
    ushort_t* __restrict__ x0)
{
  const int bidx = blockIdx.x;
  const int bb = bidx >> 7;
  const int t0 = (bidx & 127) << 6;
  const int pos0 = bb * NT + t0;
  for (int e = threadIdx.x; e < 64 * 64; e += 256) {
    int p = e >> 6, c = e & 63;
    int t = t0 + p;
    int id = (t == 0) ? 128 : wf[bb * NT + t - 1];
    x0[(size_t)(pos0 + p) * NC + c] = f2bu(embed[id * NC + c]);
  }
}

// ---------------------------------------------------------------------------
// chain5, 128-own-row tile (r3-proven body, scaled): 5 fused layers
// (d=1,2,4,8,16). 256 blocks x 640 threads (10 waves); block owns 128 rows +
// 32 halo = 160 LDS rows. Halo redundancy 1.25x (was 1.5x at 64-own) --
// r3/r4 two-point fit shows chain time ~ computed row-layers, so -17% work.
// Inner phase code identical; only tiling constants scale.
// ---------------------------------------------------------------------------
__global__ __launch_bounds__(640) void chain5_kernel(
    const ushort_t* __restrict__ xin, ushort_t* __restrict__ xout,
    ushort_t* __restrict__ gates,
    const ushort_t* __restrict__ wt,
    const float* __restrict__ cb_all, const float* __restrict__ rb_all,
    int l0, const int* __restrict__ wf, const float* __restrict__ embf)
{
  __shared__ __align__(16) ushort_t xt[160][72];   // 22.5 KB
  __shared__ __align__(16) ushort_t gt[160][72];   // 22.5 KB

  const int tid = threadIdx.x;
  const int w = tid >> 6, lane = tid & 63;      // w = tile 0..9
  const int quad = lane >> 4, c16 = lane & 15;
  const int bb = blockIdx.x >> 6;               // 64 blocks per batch
  const int t0 = (blockIdx.x & 63) << 7;        // 128 own rows
  const size_t row0 = (size_t)bb * NT;

  // ---- stage x rows t0-32 .. t0+127 ----
#pragma unroll
  for (int i = 0; i < 2; ++i) {
    int e = tid + i * 640;                      // 0..1279
    int r = e >> 3, c0 = (e & 7) * 8;
    int t = t0 - 32 + r;
    bf16x8 v;
    if (t >= 0) {
      if (embf) {
        int id = (t == 0) ? 128 : wf[row0 + t - 1];
        const float* ep = embf + id * NC + c0;
#pragma unroll
        for (int jj = 0; jj < 8; ++jj) v[jj] = (short)f2bu(ep[jj]);
      } else {
        v = *(const bf16x8*)(xin + (row0 + t) * 64 + c0);
      }
    } else { bf16x8 z = {0, 0, 0, 0, 0, 0, 0, 0}; v = z; }
    *(bf16x8*)&xt[r][c0] = v;
  }
  __syncthreads();

  for (int j = 0; j < 5; ++j) {
    const int l = l0 + j;
    const int d = 1 << j;
    const ushort_t* wcat = wt + OFF_WCAT + l * 16384;
    const ushort_t* rww  = wt + OFF_RW + l * 4096;
    const float* cb = cb_all + l * 128;
    const float* rb = rb_all + l * 64;

    // ---- phase A: A-frags from xt (cross-tile halo reads) ----
    bf16x8 af[4];
    {
      int lr = w * 16 + c16;
#pragma unroll
      for (int kk = 0; kk < 4; ++kk) {
        int rr = (kk < 2) ? lr - d : lr;
        int ch = (kk & 1) * 32 + quad * 8;
        if (rr >= 0) af[kk] = *(const bf16x8*)&xt[rr][ch];
        else { bf16x8 z = {0, 0, 0, 0, 0, 0, 0, 0}; af[kk] = z; }
      }
    }
    __syncthreads();   // all A reads done before any xt update

    // ---- phase B: GEMM1 -> gate -> gt; GEMM2 -> xt += ----
    {
      f32x4 acc[8];
#pragma unroll
      for (int q = 0; q < 4; ++q) {
        float ba = cb[q * 16 + c16], bs = cb[q * 16 + c16 + 64];
        f32x4 va = {ba, ba, ba, ba}, vb = {bs, bs, bs, bs};
        acc[q] = va; acc[4 + q] = vb;
      }
#pragma unroll
      for (int kk = 0; kk < 4; ++kk) {
        const ushort_t* wp = wcat + kk * 4096 + c16 * 32 + quad * 8;
#pragma unroll
        for (int q = 0; q < 4; ++q) {
          acc[q]     = MFMA(af[kk], *(const bf16x8*)(wp + q * 512), acc[q]);
          acc[4 + q] = MFMA(af[kk], *(const bf16x8*)(wp + q * 512 + 2048), acc[4 + q]);
        }
      }
#pragma unroll
      for (int q = 0; q < 4; ++q)
#pragma unroll
        for (int r = 0; r < 4; ++r) {
          float e2 = __expf(2.f * acc[q][r]);
          float th = (e2 - 1.f) / (e2 + 1.f);
          float sg = 1.f / (1.f + __expf(-acc[4 + q][r]));
          gt[w * 16 + quad * 4 + r][q * 16 + c16] = f2bu(th * sg);
        }

      bf16x8 gf0 = *(const bf16x8*)&gt[w * 16 + c16][quad * 8];
      bf16x8 gf1 = *(const bf16x8*)&gt[w * 16 + c16][32 + quad * 8];

      f32x4 acc2[4];
#pragma unroll
      for (int q = 0; q < 4; ++q) {
        float bv = rb[q * 16 + c16];
        f32x4 z = {bv, bv, bv, bv};
        acc2[q] = z;
      }
      const ushort_t* wp2 = rww + c16 * 32 + quad * 8;
#pragma unroll
      for (int q = 0; q < 4; ++q)
        acc2[q] = MFMA(gf0, *(const bf16x8*)(wp2 + q * 512), acc2[q]);
#pragma unroll
      for (int q = 0; q < 4; ++q)
        acc2[q] = MFMA(gf1, *(const bf16x8*)(wp2 + q * 512 + 2048), acc2[q]);
#pragma unroll
      for (int q = 0; q < 4; ++q) {
        int n = q * 16 + c16;
#pragma unroll
        for (int r = 0; r < 4; ++r) {
          int rowi = w * 16 + quad * 4 + r;
          xt[rowi][n] = f2bu(b2f(xt[rowi][n]) + acc2[q][r]);
        }
      }
    }
    __syncthreads();   // gt complete for coop write; xt complete for next j

    // ---- phase E: coop gate write (LDS rows 32..159 -> own 128 rows) ----
    {
      ushort_t* gslot = gates + (size_t)j * G_ELEMS;
#pragma unroll
      for (int i = 0; i < 2; ++i) {
        int e = tid + i * 640;
        if (e < 1024) {
          int r = e >> 3, c0 = (e & 7) * 8;
          *(bf16x8*)(gslot + (row0 + t0 + r) * 64 + c0) =
              *(const bf16x8*)&gt[32 + r][c0];
        }
      }
    }
  }
  __syncthreads();

  // ---- write back x rows 32..159 ----
#pragma unroll
  for (int i = 0; i < 2; ++i) {
    int e = tid + i * 640;
    if (e < 1024) {
      int r = e >> 3, c0 = (e & 7) * 8;
      *(bf16x8*)(xout + (row0 + t0 + r) * 64 + c0) = *(const bf16x8*)&xt[32 + r][c0];
    }
  }
}

// ---------------------------------------------------------------------------
// chain5hi, 128-own-row tile: HIGH-dilation layers (d=32..512) via stride-32
// decimation (t = i*32 + k; indexing harness-verified r2+). 256 blocks x 640
// threads; 2 segments x 128 subseq-rows per (batch, phase k).
// ---------------------------------------------------------------------------
__global__ __launch_bounds__(640) void chain5hi_kernel(
    const ushort_t* __restrict__ xin, ushort_t* __restrict__ xout,
    ushort_t* __restrict__ gates,
    const ushort_t* __restrict__ wt,
    const float* __restrict__ cb_all, const float* __restrict__ rb_all,
    int lbase, int write_x)
{
  __shared__ __align__(16) ushort_t xt[160][72];   // 22.5 KB
  __shared__ __align__(16) ushort_t gt[160][72];   // 22.5 KB

  const int tid = threadIdx.x;
  const int w = tid >> 6, lane = tid & 63;      // w = tile 0..9
  const int quad = lane >> 4, c16 = lane & 15;
  const int bb = blockIdx.x >> 6;               // 64 blocks per batch
  const int sub = blockIdx.x & 63;
  const int k = sub & 31;                       // subsequence phase
  const int i0 = (sub >> 5) << 7;               // segment base (0, 128)
  const size_t row0 = (size_t)bb * NT;

  // ---- stage: LDS row r <- x[(i0+r-32)*32 + k] ----
#pragma unroll
  for (int i = 0; i < 2; ++i) {
    int e = tid + i * 640;
    int r = e >> 3, c0 = (e & 7) * 8;
    int ii = i0 + r - 32;
    bf16x8 v;
    if (ii >= 0) v = *(const bf16x8*)(xin + (row0 + (size_t)ii * 32 + k) * 64 + c0);
    else { bf16x8 z = {0, 0, 0, 0, 0, 0, 0, 0}; v = z; }
    *(bf16x8*)&xt[r][c0] = v;
  }
  __syncthreads();

  for (int j = 0; j < 5; ++j) {
    const int l = lbase + j;
    const int d = 1 << j;                        // dilation in subseq space
    const ushort_t* wcat = wt + OFF_WCAT + l * 16384;
    const ushort_t* rww  = wt + OFF_RW + l * 4096;
    const float* cb = cb_all + l * 128;
    const float* rb = rb_all + l * 64;

    // ---- phase A ----
    bf16x8 af[4];
    {
      int lr = w * 16 + c16;
#pragma unroll
      for (int kk = 0; kk < 4; ++kk) {
        int rr = (kk < 2) ? lr - d : lr;
        int ch = (kk & 1) * 32 + quad * 8;
        if (rr >= 0) af[kk] = *(const bf16x8*)&xt[rr][ch];
        else { bf16x8 z = {0, 0, 0, 0, 0, 0, 0, 0}; af[kk] = z; }
      }
    }
    __syncthreads();

    // ---- phase B ----
    {
      f32x4 acc[8];
#pragma unroll
      for (int q = 0; q < 4; ++q) {
        float ba = cb[q * 16 + c16], bs = cb[q * 16 + c16 + 64];
        f32x4 va = {ba, ba, ba, ba}, vb = {bs, bs, bs, bs};
        acc[q] = va; acc[4 + q] = vb;
      }
#pragma unroll
      for (int kk = 0; kk < 4; ++kk) {
        const ushort_t* wp = wcat + kk * 4096 + c16 * 32 + quad * 8;
#pragma unroll
        for (int q = 0; q < 4; ++q) {
          acc[q]     = MFMA(af[kk], *(const bf16x8*)(wp + q * 512), acc[q]);
          acc[4 + q] = MFMA(af[kk], *(const bf16x8*)(wp + q * 512 + 2048), acc[4 + q]);
        }
      }
#pragma unroll
      for (int q = 0; q < 4; ++q)
#pragma unroll
        for (int r = 0; r < 4; ++r) {
          float e2 = __expf(2.f * acc[q][r]);
          float th = (e2 - 1.f) / (e2 + 1.f);
          float sg = 1.f / (1.f + __expf(-acc[4 + q][r]));
          gt[w * 16 + quad * 4 + r][q * 16 + c16] = f2bu(th * sg);
        }

      // residual GEMM (skippable only on the net's very last layer)
      if (write_x || j < 4) {
        bf16x8 gf0 = *(const bf16x8*)&gt[w * 16 + c16][quad * 8];
        bf16x8 gf1 = *(const bf16x8*)&gt[w * 16 + c16][32 + quad * 8];

        f32x4 acc2[4];
#pragma unroll
        for (int q = 0; q < 4; ++q) {
          float bv = rb[q * 16 + c16];
          f32x4 z = {bv, bv, bv, bv};
          acc2[q] = z;
        }
        const ushort_t* wp2 = rww + c16 * 32 + quad * 8;
#pragma unroll
        for (int q = 0; q < 4; ++q)
          acc2[q] = MFMA(gf0, *(const bf16x8*)(wp2 + q * 512), acc2[q]);
#pragma unroll
        for (int q = 0; q < 4; ++q)
          acc2[q] = MFMA(gf1, *(const bf16x8*)(wp2 + q * 512 + 2048), acc2[q]);
#pragma unroll
        for (int q = 0; q < 4; ++q) {
          int n = q * 16 + c16;
#pragma unroll
          for (int r = 0; r < 4; ++r) {
            int rowi = w * 16 + quad * 4 + r;
            xt[rowi][n] = f2bu(b2f(xt[rowi][n]) + acc2[q][r]);
          }
        }
      }
    }
    __syncthreads();

    // ---- phase E: coop gate write (own 128 subseq rows, decimated addr) ----
    {
      ushort_t* gslot = gates + (size_t)j * G_ELEMS;
#pragma unroll
      for (int i = 0; i < 2; ++i) {
        int e = tid + i * 640;
        if (e < 1024) {
          int r = e >> 3, c0 = (e & 7) * 8;
          *(bf16x8*)(gslot + (row0 + (size_t)(i0 + r) * 32 + k) * 64 + c0) =
              *(const bf16x8*)&gt[32 + r][c0];
        }
      }
    }
  }
  __syncthreads();

  // ---- write back x rows (i0 .. i0+127)*32 + k ----
  if (write_x) {
#pragma unroll
    for (int i = 0; i < 2; ++i) {
      int e = tid + i * 640;
      if (e < 1024) {
        int r = e >> 3, c0 = (e & 7) * 8;
        *(bf16x8*)(xout + (row0 + (size_t)(i0 + r) * 32 + k) * 64 + c0) =
            *(const bf16x8*)&xt[32 + r][c0];
      }
    }
  }
}

// ---------------------------------------------------------------------------
// FUSED skip-over-all-30-layers + head (ROUND-5/6/9 PROVEN FORM, 76us):
// K=1920 GEMM with single-barrier double-buffered weight staging + depth-1
// gate prefetch, fp32 accumulation, then the round-1-proven head phases.
// ---------------------------------------------------------------------------
__global__ __launch_bounds__(256) void skip30_head_kernel(
    const ushort_t* __restrict__ gates,   // 30 slots
    const ushort_t* __restrict__ wt,
    const float* __restrict__ sbtot,      // 256 totals (all 30 layers)
    const float* __restrict__ b0, const float* __restrict__ b1,
    const int* __restrict__ wf, const int* __restrict__ lens,
    float* __restrict__ loss)
{
  __shared__ __align__(16) ushort_t wbuf[2][8192];    // 32 KB (double buffer)
  __shared__ __align__(16) ushort_t tile[64][264];    // 33.8 KB
  const int tid = threadIdx.x;
  const int w = tid >> 6, lane = tid & 63;
  const int quad = lane >> 4, c16 = lane & 15;
  const int bb = blockIdx.x >> 7;
  const int t0 = (blockIdx.x & 127) << 6;
  const int tb = t0 + w * 16;
  const size_t row0 = (size_t)bb * NT;
  const int mylen = lens[bb];
  const ushort_t* swg = wt + OFF_SWG;

  // ---- phase 1: skip = sum over 60 K-chunks (fp32 regs) ----
  f32x4 acc[16];
#pragma unroll
  for (int nt = 0; nt < 16; ++nt) { f32x4 z = {0.f, 0.f, 0.f, 0.f}; acc[nt] = z; }

  const size_t arow = (row0 + tb + c16) * 64;
  bf16x8 wreg[4];
#pragma unroll
  for (int i = 0; i < 4; ++i)
    wreg[i] = ((const bf16x8*)swg)[tid + i * 256];
  bf16x8 af = *(const bf16x8*)(gates + arow + quad * 8);
  int cur = 0;

  for (int kk = 0; kk < 60; ++kk) {
    // commit staged regs for chunk kk
#pragma unroll
    for (int i = 0; i < 4; ++i)
      ((bf16x8*)wbuf[cur])[tid + i * 256] = wreg[i];
    // prefetch chunk kk+1 (weights + gate frag)
    int kn = (kk + 1 < 60) ? kk + 1 : 59;
#pragma unroll
    for (int i = 0; i < 4; ++i)
      wreg[i] = ((const bf16x8*)(swg + (size_t)kn * 8192))[tid + i * 256];
    bf16x8 afn = *(const bf16x8*)(gates + (size_t)(kn >> 1) * G_ELEMS + arow +
                                  (kn & 1) * 32 + quad * 8);
    __syncthreads();   // wbuf[cur] fully written (single barrier per iter)
    const ushort_t* wp = wbuf[cur] + c16 * 32 + quad * 8;
#pragma unroll
    for (int nt = 0; nt < 16; ++nt)
      acc[nt] = MFMA(af, *(const bf16x8*)(wp + nt * 512), acc[nt]);
    af = afn; cur ^= 1;
  }

  // ---- phase 2: skip + total bias -> tile (bf16, wave-private rows) ----
#pragma unroll
  for (int nt = 0; nt < 16; ++nt) {
    int n = nt * 16 + c16;
    float sbn = sbtot[n];
#pragma unroll
    for (int r = 0; r < 4; ++r)
      tile[w * 16 + quad * 4 + r][n] = f2bu(acc[nt][r] + sbn);
  }

  // ---- phase 3: hid = relu(skip @ w0 + b0) -> tile in place ----
  const ushort_t* w0T = wt + OFF_W0;
  f32x4 accA[16];
#pragma unroll
  for (int nt = 0; nt < 16; ++nt) {
    float bv = b0[nt * 16 + c16];
    f32x4 z = {bv, bv, bv, bv};
    accA[nt] = z;
  }
  for (int kk = 0; kk < 8; ++kk) {
#pragma unroll
    for (int i = 0; i < 4; ++i)
      ((bf16x8*)wbuf[0])[tid + i * 256] = ((const bf16x8*)(w0T + kk * 8192))[tid + i * 256];
    __syncthreads();
    bf16x8 hf = *(const bf16x8*)&tile[w * 16 + c16][kk * 32 + quad * 8];
    const ushort_t* wp = wbuf[0] + c16 * 32 + quad * 8;
#pragma unroll
    for (int nt = 0; nt < 16; ++nt)
      accA[nt] = MFMA(hf, *(const bf16x8*)(wp + nt * 512), accA[nt]);
    __syncthreads();
  }
#pragma unroll
  for (int nt = 0; nt < 16; ++nt)
#pragma unroll
    for (int r = 0; r < 4; ++r)
      tile[w * 16 + quad * 4 + r][nt * 16 + c16] = f2bu(fmaxf(accA[nt][r], 0.f));

  // ---- phase 4: logits = hid @ w1 + b1 ----
  const ushort_t* w1T = wt + OFF_W1;
  f32x4 acc2[16];
#pragma unroll
  for (int nt = 0; nt < 16; ++nt) {
    float bv = b1[nt * 16 + c16];
    f32x4 z = {bv, bv, bv, bv};
    acc2[nt] = z;
  }
  for (int kk = 0; kk < 8; ++kk) {
#pragma unroll
    for (int i = 0; i < 4; ++i)
      ((bf16x8*)wbuf[0])[tid + i * 256] = ((const bf16x8*)(w1T + kk * 8192))[tid + i * 256];
    __syncthreads();
    bf16x8 hf = *(const bf16x8*)&tile[w * 16 + c16][kk * 32 + quad * 8];
    const ushort_t* wp = wbuf[0] + c16 * 32 + quad * 8;
#pragma unroll
    for (int nt = 0; nt < 16; ++nt)
      acc2[nt] = MFMA(hf, *(const bf16x8*)(wp + nt * 512), acc2[nt]);
    __syncthreads();
  }

  int lblv[4];
#pragma unroll
  for (int r = 0; r < 4; ++r)
    lblv[r] = wf[row0 + tb + quad * 4 + r];

  // ---- phase 5: two-pass log-softmax + masked CE ----
  float local = 0.f;
#pragma unroll
  for (int r = 0; r < 4; ++r) {
    float m = -1e30f, tv = -1e30f;
#pragma unroll
    for (int nt = 0; nt < 16; ++nt) {
      float v = acc2[nt][r];
      m = fmaxf(m, v);
      if (lblv[r] == nt * 16 + c16) tv = v;
    }
#pragma unroll
    for (int dd = 1; dd < 16; dd <<= 1) m = fmaxf(m, __shfl_xor(m, dd));
    float s = 0.f;
#pragma unroll
    for (int nt = 0; nt < 16; ++nt) s += __expf(acc2[nt][r] - m);
#pragma unroll
    for (int dd = 1; dd < 16; dd <<= 1) {
      s += __shfl_xor(s, dd);
      tv = fmaxf(tv, __shfl_xor(tv, dd));
    }
    int t = tb + quad * 4 + r;
    if (c16 == 0 && t < mylen) local += (m + __logf(s)) - tv;
  }
#pragma unroll
  for (int dd = 1; dd < 64; dd <<= 1) local += __shfl_xor(local, dd);
  if (lane == 0 && local != 0.f) atomicAdd(loss, local);
}

// ---------------------------------------------------------------------------
// Skip-group GEMM (ROUND-3 PROVEN). FALLBACK (small workspace) ONLY.
// ---------------------------------------------------------------------------
__global__ __launch_bounds__(256) void skip_kernel(
    ushort_t* __restrict__ skip, const ushort_t* __restrict__ gates,
    const ushort_t* __restrict__ swg, const float* __restrict__ sbg,
    int first)
{
  __shared__ __align__(16) ushort_t wbuf[8192];   // 16 KB chunk
  const int tid = threadIdx.x;
  const int w = tid >> 6, lane = tid & 63;
  const int quad = lane >> 4, c16 = lane & 15;
  const int bb = blockIdx.x >> 7;
  const int t0 = (blockIdx.x & 127) << 6;
  const int tb = t0 + w * 16;
  const size_t row0 = (size_t)bb * NT;

  f32x4 acc[16];
#pragma unroll
  for (int nt = 0; nt < 16; ++nt) { f32x4 z = {0.f, 0.f, 0.f, 0.f}; acc[nt] = z; }

  const size_t arow = (row0 + tb + c16) * 64;
  for (int kk = 0; kk < 10; ++kk) {
#pragma unroll
    for (int i = 0; i < 4; ++i)
      ((bf16x8*)wbuf)[tid + i * 256] = ((const bf16x8*)(swg + kk * 8192))[tid + i * 256];
    __syncthreads();

    int slot = kk >> 1;
    bf16x8 af = *(const bf16x8*)(gates + (size_t)slot * G_ELEMS + arow +
                                 (kk & 1) * 32 + quad * 8);
    const ushort_t* wp = wbuf + c16 * 32 + quad * 8;
#pragma unroll
    for (int nt = 0; nt < 16; ++nt)
      acc[nt] = MFMA(af, *(const bf16x8*)(wp + nt * 512), acc[nt]);
    __syncthreads();
  }

#pragma unroll
  for (int nt = 0; nt < 16; ++nt) {
    int n = nt * 16 + c16;
    float sbn = sbg[n];
#pragma unroll
    for (int r = 0; r < 4; ++r) {
      size_t idx = (row0 + tb + quad * 4 + r) * 256 + n;
      float old = first ? 0.f : b2f(skip[idx]);
      skip[idx] = f2bu(old + acc[nt][r] + sbn);
    }
  }
}

// ---------------------------------------------------------------------------
// Head from materialized skip (ROUND-1 PROVEN). FALLBACK ONLY.
// ---------------------------------------------------------------------------
__global__ __launch_bounds__(256) void head_kernel(
    const ushort_t* __restrict__ skip,
    const ushort_t* __restrict__ w0T, const float* __restrict__ b0,
    const ushort_t* __restrict__ w1T, const float* __restrict__ b1,
    const int* __restrict__ wf, const int* __restrict__ lens,
    float* __restrict__ loss)
{
  __shared__ __align__(16) ushort_t wbuf[8192];       // 16 KB chunk
  __shared__ __align__(16) ushort_t tile[64][264];    // 33.8 KB
  const int tid = threadIdx.x;
  const int w = tid >> 6, lane = tid & 63;
  const int quad = lane >> 4, c16 = lane & 15;
  const int bb = blockIdx.x >> 7;
  const int t0 = (blockIdx.x & 127) << 6;
  const int tb = t0 + w * 16;
  const size_t row0 = (size_t)bb * NT;
  const int mylen = lens[bb];

#pragma unroll
  for (int i = 0; i < 8; ++i) {
    int e = lane + i * 64;                  // 0..511
    int r = e >> 5, c0 = (e & 31) * 8;
    *(bf16x8*)&tile[w * 16 + r][c0] =
        *(const bf16x8*)(skip + (row0 + t0 + w * 16 + r) * 256 + c0);
  }

  f32x4 accA[16];
#pragma unroll
  for (int nt = 0; nt < 16; ++nt) {
    float bv = b0[nt * 16 + c16];
    f32x4 z = {bv, bv, bv, bv};
    accA[nt] = z;
  }
  for (int kk = 0; kk < 8; ++kk) {
#pragma unroll
    for (int i = 0; i < 4; ++i)
      ((bf16x8*)wbuf)[tid + i * 256] = ((const bf16x8*)(w0T + kk * 8192))[tid + i * 256];
    __syncthreads();
    bf16x8 af = *(const bf16x8*)&tile[w * 16 + c16][kk * 32 + quad * 8];
    const ushort_t* wp = wbuf + c16 * 32 + quad * 8;
#pragma unroll
    for (int nt = 0; nt < 16; ++nt)
      accA[nt] = MFMA(af, *(const bf16x8*)(wp + nt * 512), accA[nt]);
    __syncthreads();
  }
#pragma unroll
  for (int nt = 0; nt < 16; ++nt)
#pragma unroll
    for (int r = 0; r < 4; ++r)
      tile[w * 16 + quad * 4 + r][nt * 16 + c16] = f2bu(fmaxf(accA[nt][r], 0.f));

  f32x4 acc2[16];
#pragma unroll
  for (int nt = 0; nt < 16; ++nt) {
    float bv = b1[nt * 16 + c16];
    f32x4 z = {bv, bv, bv, bv};
    acc2[nt] = z;
  }
  for (int kk = 0; kk < 8; ++kk) {
#pragma unroll
    for (int i = 0; i < 4; ++i)
      ((bf16x8*)wbuf)[tid + i * 256] = ((const bf16x8*)(w1T + kk * 8192))[tid + i * 256];
    __syncthreads();
    bf16x8 hf = *(const bf16x8*)&tile[w * 16 + c16][kk * 32 + quad * 8];
    const ushort_t* wp = wbuf + c16 * 32 + quad * 8;
#pragma unroll
    for (int nt = 0; nt < 16; ++nt)
      acc2[nt] = MFMA(hf, *(const bf16x8*)(wp + nt * 512), acc2[nt]);
    __syncthreads();
  }

  int lblv[4];
#pragma unroll
  for (int r = 0; r < 4; ++r)
    lblv[r] = wf[row0 + tb + quad * 4 + r];

  float local = 0.f;
#pragma unroll
  for (int r = 0; r < 4; ++r) {
    float m = -1e30f, tv = -1e30f;
#pragma unroll
    for (int nt = 0; nt < 16; ++nt) {
      float v = acc2[nt][r];
      m = fmaxf(m, v);
      if (lblv[r] == nt * 16 + c16) tv = v;
    }
#pragma unroll
    for (int dd = 1; dd < 16; dd <<= 1) m = fmaxf(m, __shfl_xor(m, dd));
    float s = 0.f;
#pragma unroll
    for (int nt = 0; nt < 16; ++nt) s += __expf(acc2[nt][r] - m);
#pragma unroll
    for (int dd = 1; dd < 16; dd <<= 1) {
      s += __shfl_xor(s, dd);
      tv = fmaxf(tv, __shfl_xor(tv, dd));
    }
    int t = tb + quad * 4 + r;
    if (c16 == 0 && t < mylen) local += (m + __logf(s)) - tv;
  }
#pragma unroll
  for (int dd = 1; dd < 64; dd <<= 1) local += __shfl_xor(local, dd);
  if (lane == 0 && local != 0.f) atomicAdd(loss, local);
}

__global__ void finalize_kernel(const int* __restrict__ lens,
                                float* __restrict__ out)
{
  if (threadIdx.x == 0) {
    float den = 0.f;
    for (int b = 0; b < NB; ++b) {
      int l = lens[b];
      if (l > NT) l = NT;
      den += (float)l;
    }
    out[0] = out[0] / fmaxf(den, 1.f);
  }
}

// ---------------------------------------------------------------------------
extern "C" void kernel_launch(void* const* d_in, const int* in_sizes, int n_in,
                              void* d_out, int out_size, void* d_ws, size_t ws_size,
                              hipStream_t stream) {
  const int*   wf     = (const int*)d_in[0];
  const int*   lens   = (const int*)d_in[1];
  const float* embed  = (const float*)d_in[2];
  const float* conv_w = (const float*)d_in[3];
  const float* conv_b = (const float*)d_in[4];
  const float* res_w  = (const float*)d_in[5];
  const float* res_b  = (const float*)d_in[6];
  const float* skip_w = (const float*)d_in[7];
  const float* skip_b = (const float*)d_in[8];
  const float* w0     = (const float*)d_in[9];
  const float* b0     = (const float*)d_in[10];
  const float* w1     = (const float*)d_in[11];
  const float* b1     = (const float*)d_in[12];

  float* out = (float*)d_out;
  if (ws_size < WS_SMALL) {
    sentinel_kernel<<<1, 64, 0, stream>>>(out);
    return;
  }
  const bool big = (ws_size >= WS_BIG);

  if (big) {
    // layout: x0, x1, gates[30], wt, sbg[1792]
    ushort_t* x0    = (ushort_t*)d_ws;
    ushort_t* x1    = x0 + X_ELEMS;
    ushort_t* gates = x1 + X_ELEMS;                   // 30 x 4 MB
    ushort_t* wt    = gates + 30 * (size_t)G_ELEMS;
    float*    sbg   = (float*)(wt + TOTAL_W);

    prep_kernel<<<(N_PREP + 255) / 256, 256, 0, stream>>>(
        conv_w, res_w, skip_w, w0, w1, skip_b, wt, sbg, out);

    const ushort_t* xin = x0;
    ushort_t* xout = x1;
    for (int blk = 0; blk < 3; ++blk) {
      const int l0 = blk * 10;
      chain5_kernel<<<256, 640, 0, stream>>>(
          xin, xout, gates + (size_t)(2 * blk) * 5 * G_ELEMS,
          wt, conv_b, res_b, l0, wf, blk == 0 ? embed : nullptr);
      { const ushort_t* t = xout; xout = (ushort_t*)xin; xin = t; }
      chain5hi_kernel<<<256, 640, 0, stream>>>(
          xin, xout, gates + (size_t)(2 * blk + 1) * 5 * G_ELEMS,
          wt, conv_b, res_b, l0 + 5, blk < 2 ? 1 : 0);
      { const ushort_t* t = xout; xout = (ushort_t*)xin; xin = t; }
    }

    skip30_head_kernel<<<512, 256, 0, stream>>>(
        gates, wt, sbg + 1536, b0, b1, wf, lens, out);
    finalize_kernel<<<1, 64, 0, stream>>>(lens, out);
  } else {
    // Fallback: x0, x1, skip, gates[5], wt, sbg
    ushort_t* x0    = (ushort_t*)d_ws;
    ushort_t* x1    = x0 + X_ELEMS;
    ushort_t* skip  = x1 + X_ELEMS;
    ushort_t* gates = skip + SK_ELEMS;
    ushort_t* wt    = gates + 5 * (size_t)G_ELEMS;
    float*    sbg   = (float*)(wt + TOTAL_W);

    prep_kernel<<<(N_PREP + 255) / 256, 256, 0, stream>>>(
        conv_w, res_w, skip_w, w0, w1, skip_b, wt, sbg, out);
    embed_kernel<<<512, 256, 0, stream>>>(wf, embed, x0);

    const ushort_t* xin = x0;
    ushort_t* xout = x1;
    for (int blk = 0; blk < 3; ++blk) {
      const int l0 = blk * 10;
      chain5_kernel<<<256, 640, 0, stream>>>(
          xin, xout, gates, wt, conv_b, res_b, l0, wf, nullptr);
      { const ushort_t* t = xout; xout = (ushort_t*)xin; xin = t; }
      skip_kernel<<<512, 256, 0, stream>>>(
          skip, gates, wt + OFF_SWG + (size_t)(2 * blk) * 81920,
          sbg + (size_t)(2 * blk) * 256, blk == 0 ? 1 : 0);
      chain5hi_kernel<<<256, 640, 0, stream>>>(
          xin, xout, gates, wt, conv_b, res_b, l0 + 5, blk < 2 ? 1 : 0);
      { const ushort_t* t = xout; xout = (ushort_t*)xin; xin = t; }
      skip_kernel<<<512, 256, 0, stream>>>(
          skip, gates, wt + OFF_SWG + (size_t)(2 * blk + 1) * 81920,
          sbg + (size_t)(2 * blk + 1) * 256, 0);
    }

    head_kernel<<<512, 256, 0, stream>>>(
        skip, wt + OFF_W0, b0, wt + OFF_W1, b1, wf, lens, out);
    finalize_kernel<<<1, 64, 0, stream>>>(lens, out);
  }
}

// Round 12
// 416.019 us; speedup vs baseline: 1.0406x; 1.0406x over previous
//
#include <hip/hip_runtime.h>

#define NB 4
#define NT 8192
#define NC 64
#define NS 256
#define NV 256
#define NL 30

typedef __attribute__((ext_vector_type(8))) short bf16x8;
typedef __attribute__((ext_vector_type(4))) float f32x4;
typedef unsigned short ushort_t;

#define MFMA(a, b, c) __builtin_amdgcn_mfma_f32_16x16x32_bf16(a, b, c, 0, 0, 0)

// weight arena (bf16 elems)
#define OFF_WCAT 0
#define SZ_WCAT  (NL * 16384)            // swizzled [l][kk=4][n=128][j=32]
#define OFF_RW   (OFF_WCAT + SZ_WCAT)
#define SZ_RW    (NL * 4096)             // swizzled [l][kk=2][n=64][j=32]
#define OFF_SWG  (OFF_RW + SZ_RW)
#define SZ_SWG   (6 * 81920)             // [kkall=60][n=256][j=32] (6 groups x 10)
#define OFF_W0   (OFF_SWG + SZ_SWG)      // [kk=8][n=256][j=32]
#define OFF_W1   (OFF_W0 + 65536)        // [kk=8][n=256][j=32]
#define TOTAL_W  (OFF_W1 + 65536)        // 1,236,992 elems (2.42 MB)
#define N_PREP   (TOTAL_W + 1792)        // + sbg[6][256] + sbtot[256] fp32

#define X_ELEMS  (NB * NT * NC)          // 2,097,152 (4 MB bf16)
#define SK_ELEMS (NB * NT * NS)          // 8,388,608 (16 MB bf16)
#define G_ELEMS  (NB * NT * NC)          // gate slot (4 MB bf16)

// small path (round-3 proven): 5 shared gate slots + skip buffer
#define WS_SMALL ((size_t)(2 * X_ELEMS + SK_ELEMS + 5 * G_ELEMS + TOTAL_W) * 2 \
                  + 1792 * 4)
// big path: 30 gate slots, no skip buffer
#define WS_BIG   ((size_t)(2 * X_ELEMS + 30 * G_ELEMS + TOTAL_W) * 2 + 1792 * 4)

__device__ inline ushort_t f2bu(float f) {
  union { float f; unsigned u; } v; v.f = f;
  unsigned r = v.u + 0x7FFFu + ((v.u >> 16) & 1u);
  return (ushort_t)(r >> 16);
}
__device__ inline float b2f(ushort_t h) {
  union { unsigned u; float f; } v; v.u = ((unsigned)h) << 16; return v.f;
}

__global__ void sentinel_kernel(float* __restrict__ out) {
  if (threadIdx.x == 0) out[0] = -1234.0f;
}

// ---------------------------------------------------------------------------
// prep: weight swizzle + bias sums + out[0]=0 (zero_kernel folded in).
// ---------------------------------------------------------------------------
__global__ __launch_bounds__(256) void prep_kernel(
    const float* __restrict__ cw, const float* __restrict__ rw,
    const float* __restrict__ sw, const float* __restrict__ w0,
    const float* __restrict__ w1, const float* __restrict__ sb_all,
    ushort_t* __restrict__ wt, float* __restrict__ sbg,
    float* __restrict__ out0)
{
  int idx = blockIdx.x * 256 + threadIdx.x;
  if (idx == 0) out0[0] = 0.f;
  if (idx >= N_PREP) return;
  if (idx >= TOTAL_W) {
    int j = idx - TOTAL_W;
    if (j < 1536) {
      int g = j >> 8, n = j & 255;
      float s = 0.f;
#pragma unroll
      for (int jj = 0; jj < 5; ++jj) s += sb_all[(5 * g + jj) * 256 + n];
      sbg[j] = s;
    } else {
      int n = j - 1536;
      float s = 0.f;
      for (int jj = 0; jj < NL; ++jj) s += sb_all[jj * 256 + n];
      sbg[j] = s;                         // total bias over all 30 layers
    }
    return;
  }
  float v;
  if (idx < OFF_RW) {
    int e = idx; int l = e >> 14; int r = e & 16383;
    int kk = r >> 12, n = (r >> 5) & 127, j = r & 31;
    int k = kk * 32 + j, tap = k >> 6, c = k & 63;
    v = cw[(((l * 2 + tap) << 6) + c) * 128 + n];
  } else if (idx < OFF_SWG) {
    int e = idx - OFF_RW; int l = e >> 12; int r = e & 4095;
    int kk = r >> 11, n = (r >> 5) & 63, j = r & 31;
    int k = kk * 32 + j;
    v = rw[((l << 6) + k) * 64 + n];
  } else if (idx < OFF_W0) {
    int e = idx - OFF_SWG; int g = e / 81920; int r = e % 81920;
    int kk = r >> 13; int rem = r & 8191;
    int n = rem >> 5, jj = rem & 31;
    int k = kk * 32 + jj;                       // 0..319
    v = sw[(size_t)(320 * g + k) * 256 + n];
  } else if (idx < OFF_W1) {
    int e = idx - OFF_W0;
    int kk = e >> 13; int rem = e & 8191;
    int n = rem >> 5, jj = rem & 31;
    int k = kk * 32 + jj;
    v = w0[k * 256 + n];
  } else {
    int e = idx - OFF_W1;
    int kk = e >> 13; int rem = e & 8191;
    int n = rem >> 5, jj = rem & 31;
    int k = kk * 32 + jj;
    v = w1[k * 256 + n];
  }
  wt[idx] = f2bu(v);
}

// ---------------------------------------------------------------------------
// embed: FALLBACK path only (big path fuses embedding into chain5 blk0).
// ---------------------------------------------------------------------------
__global__ __launch_bounds__(256) void embed_kernel(
    const int* __restrict__ wf, const float* __restrict__ embed,
    ushort_t* __restrict__ x0)
{
  const int bidx = blockIdx.x;
  const int bb = bidx >> 7;
  const int t0 = (bidx & 127) << 6;
  const int pos0 = bb * NT + t0;
  for (int e = threadIdx.x; e < 64 * 64; e += 256) {
    int p = e >> 6, c = e & 63;
    int t = t0 + p;
    int id = (t == 0) ? 128 : wf[bb * NT + t - 1];
    x0[(size_t)(pos0 + p) * NC + c] = f2bu(embed[id * NC + c]);
  }
}

// ---------------------------------------------------------------------------
// chain5 (ROUND-9 PROVEN, 51us): 5 fused layers (d=1,2,4,8,16). 512 blocks x
// 384 threads; block owns 64 rows + 32 halo; gates -> slots 0-4 of base.
// Optional fused embedding (embf != nullptr): identical math to embed_kernel.
// ---------------------------------------------------------------------------
__global__ __launch_bounds__(384) void chain5_kernel(
    const ushort_t* __restrict__ xin, ushort_t* __restrict__ xout,
    ushort_t* __restrict__ gates,
    const ushort_t* __restrict__ wt,
    const float* __restrict__ cb_all, const float* __restrict__ rb_all,
    int l0, const int* __restrict__ wf, const float* __restrict__ embf)
{
  __shared__ __align__(16) ushort_t xt[96][72];   // 13.5 KB
  __shared__ __align__(16) ushort_t gt[96][72];   // 13.5 KB

  const int tid = threadIdx.x;
  const int w = tid >> 6, lane = tid & 63;      // w = tile 0..5
  const int quad = lane >> 4, c16 = lane & 15;
  const int bb = blockIdx.x >> 7;               // 128 blocks per batch
  const int t0 = (blockIdx.x & 127) << 6;       // 64 own rows
  const size_t row0 = (size_t)bb * NT;

  // ---- stage x rows t0-32 .. t0+63 ----
#pragma unroll
  for (int i = 0; i < 2; ++i) {
    int e = tid + i * 384;
    int r = e >> 3, c0 = (e & 7) * 8;
    int t = t0 - 32 + r;
    bf16x8 v;
    if (t >= 0) {
      if (embf) {
        int id = (t == 0) ? 128 : wf[row0 + t - 1];
        const float* ep = embf + id * NC + c0;
#pragma unroll
        for (int jj = 0; jj < 8; ++jj) v[jj] = (short)f2bu(ep[jj]);
      } else {
        v = *(const bf16x8*)(xin + (row0 + t) * 64 + c0);
      }
    } else { bf16x8 z = {0, 0, 0, 0, 0, 0, 0, 0}; v = z; }
    *(bf16x8*)&xt[r][c0] = v;
  }
  __syncthreads();

  for (int j = 0; j < 5; ++j) {
    const int l = l0 + j;
    const int d = 1 << j;
    const ushort_t* wcat = wt + OFF_WCAT + l * 16384;
    const ushort_t* rww  = wt + OFF_RW + l * 4096;
    const float* cb = cb_all + l * 128;
    const float* rb = rb_all + l * 64;

    // ---- phase A: A-frags from xt (cross-tile halo reads) ----
    bf16x8 af[4];
    {
      int lr = w * 16 + c16;
#pragma unroll
      for (int kk = 0; kk < 4; ++kk) {
        int rr = (kk < 2) ? lr - d : lr;
        int ch = (kk & 1) * 32 + quad * 8;
        if (rr >= 0) af[kk] = *(const bf16x8*)&xt[rr][ch];
        else { bf16x8 z = {0, 0, 0, 0, 0, 0, 0, 0}; af[kk] = z; }
      }
    }
    __syncthreads();   // all A reads done before any xt update

    // ---- phase B: GEMM1 -> gate -> gt; GEMM2 -> xt += ----
    {
      f32x4 acc[8];
#pragma unroll
      for (int q = 0; q < 4; ++q) {
        float ba = cb[q * 16 + c16], bs = cb[q * 16 + c16 + 64];
        f32x4 va = {ba, ba, ba, ba}, vb = {bs, bs, bs, bs};
        acc[q] = va; acc[4 + q] = vb;
      }
#pragma unroll
      for (int kk = 0; kk < 4; ++kk) {
        const ushort_t* wp = wcat + kk * 4096 + c16 * 32 + quad * 8;
#pragma unroll
        for (int q = 0; q < 4; ++q) {
          acc[q]     = MFMA(af[kk], *(const bf16x8*)(wp + q * 512), acc[q]);
          acc[4 + q] = MFMA(af[kk], *(const bf16x8*)(wp + q * 512 + 2048), acc[4 + q]);
        }
      }
#pragma unroll
      for (int q = 0; q < 4; ++q)
#pragma unroll
        for (int r = 0; r < 4; ++r) {
          float e2 = __expf(2.f * acc[q][r]);
          float th = (e2 - 1.f) / (e2 + 1.f);
          float sg = 1.f / (1.f + __expf(-acc[4 + q][r]));
          gt[w * 16 + quad * 4 + r][q * 16 + c16] = f2bu(th * sg);
        }

      bf16x8 gf0 = *(const bf16x8*)&gt[w * 16 + c16][quad * 8];
      bf16x8 gf1 = *(const bf16x8*)&gt[w * 16 + c16][32 + quad * 8];

      f32x4 acc2[4];
#pragma unroll
      for (int q = 0; q < 4; ++q) {
        float bv = rb[q * 16 + c16];
        f32x4 z = {bv, bv, bv, bv};
        acc2[q] = z;
      }
      const ushort_t* wp2 = rww + c16 * 32 + quad * 8;
#pragma unroll
      for (int q = 0; q < 4; ++q)
        acc2[q] = MFMA(gf0, *(const bf16x8*)(wp2 + q * 512), acc2[q]);
#pragma unroll
      for (int q = 0; q < 4; ++q)
        acc2[q] = MFMA(gf1, *(const bf16x8*)(wp2 + q * 512 + 2048), acc2[q]);
#pragma unroll
      for (int q = 0; q < 4; ++q) {
        int n = q * 16 + c16;
#pragma unroll
        for (int r = 0; r < 4; ++r) {
          int rowi = w * 16 + quad * 4 + r;
          xt[rowi][n] = f2bu(b2f(xt[rowi][n]) + acc2[q][r]);
        }
      }
    }
    __syncthreads();   // gt complete for coop write; xt complete for next j

    // ---- phase E: coop gate write (rows 32..95 -> own 64 rows) ----
    {
      ushort_t* gslot = gates + (size_t)j * G_ELEMS;
      int e = tid;
      {
        int r = e >> 3, c0 = (e & 7) * 8;
        *(bf16x8*)(gslot + (row0 + t0 + r) * 64 + c0) =
            *(const bf16x8*)&gt[32 + r][c0];
      }
      e = tid + 384;
      if (e < 512) {
        int r = e >> 3, c0 = (e & 7) * 8;
        *(bf16x8*)(gslot + (row0 + t0 + r) * 64 + c0) =
            *(const bf16x8*)&gt[32 + r][c0];
      }
    }
  }
  __syncthreads();

  // ---- write back x rows 32..95 ----
  {
    int e = tid;
    {
      int r = e >> 3, c0 = (e & 7) * 8;
      *(bf16x8*)(xout + (row0 + t0 + r) * 64 + c0) = *(const bf16x8*)&xt[32 + r][c0];
    }
    e = tid + 384;
    if (e < 512) {
      int r = e >> 3, c0 = (e & 7) * 8;
      *(bf16x8*)(xout + (row0 + t0 + r) * 64 + c0) = *(const bf16x8*)&xt[32 + r][c0];
    }
  }
}

// ---------------------------------------------------------------------------
// Single high-dilation layer (d >= 32): ROUND-0 PROVEN (~8.4us incl gap).
// 512 blocks x 256 threads; writes its gates to a DEDICATED slot.
// ---------------------------------------------------------------------------
__global__ __launch_bounds__(256, 4) void layer_kernel(
    const ushort_t* __restrict__ xin, ushort_t* __restrict__ xout,
    ushort_t* __restrict__ gate_out,
    const ushort_t* __restrict__ wcat_s, const float* __restrict__ cb,
    const ushort_t* __restrict__ rww,    const float* __restrict__ rb,
    int d, int write_res)
{
  __shared__ __align__(16) ushort_t lwc[16384];    // 32 KB conv weights
  __shared__ __align__(16) ushort_t gt[64][72];    // 9 KB gate tile

  const int tid = threadIdx.x;
  const int w = tid >> 6, lane = tid & 63;
  const int quad = lane >> 4, c16 = lane & 15;
  const int bb = blockIdx.x >> 7;
  const int t0 = (blockIdx.x & 127) << 6;
  const int tb = t0 + w * 16;
  const size_t row0 = (size_t)bb * NT;

  {
    bf16x8* dst = (bf16x8*)lwc;
    const bf16x8* s1 = (const bf16x8*)wcat_s;
#pragma unroll
    for (int i = 0; i < 8; ++i) dst[tid + i * 256] = s1[tid + i * 256];
  }

  const int tA = tb + c16;
  bf16x8 af[4];
#pragma unroll
  for (int kk = 0; kk < 4; ++kk) {
    int ts = (kk < 2) ? (tA - d) : tA;
    int ch = (kk & 1) * 32 + quad * 8;
    if (ts >= 0) {
      af[kk] = *(const bf16x8*)(xin + (row0 + ts) * 64 + ch);
    } else {
      bf16x8 z = {0, 0, 0, 0, 0, 0, 0, 0};
      af[kk] = z;
    }
  }
  __syncthreads();

#pragma unroll
  for (int q = 0; q < 4; ++q) {
    int na = q * 16 + c16;
    int nb2 = na + 64;
    float ba = cb[na], bs = cb[nb2];
    f32x4 va = {ba, ba, ba, ba}, vb = {bs, bs, bs, bs};
#pragma unroll
    for (int kk = 0; kk < 4; ++kk) {
      va = MFMA(af[kk], *(const bf16x8*)&lwc[kk * 4096 + na * 32 + quad * 8], va);
      vb = MFMA(af[kk], *(const bf16x8*)&lwc[kk * 4096 + nb2 * 32 + quad * 8], vb);
    }
#pragma unroll
    for (int r = 0; r < 4; ++r) {
      float e2 = __expf(2.f * va[r]);
      float th = (e2 - 1.f) / (e2 + 1.f);
      float sg = 1.f / (1.f + __expf(-vb[r]));
      gt[w * 16 + quad * 4 + r][q * 16 + c16] = f2bu(th * sg);
    }
  }

  bf16x8 gf0 = *(const bf16x8*)&gt[w * 16 + c16][quad * 8];
  bf16x8 gf1 = *(const bf16x8*)&gt[w * 16 + c16][32 + quad * 8];

  if (write_res) {
    const ushort_t* wp2 = rww + c16 * 32 + quad * 8;
#pragma unroll
    for (int q = 0; q < 4; ++q) {
      int n = q * 16 + c16;
      float bv = rb[n];
      f32x4 acc = {bv, bv, bv, bv};
      acc = MFMA(gf0, *(const bf16x8*)(wp2 + q * 512), acc);
      acc = MFMA(gf1, *(const bf16x8*)(wp2 + q * 512 + 2048), acc);
#pragma unroll
      for (int r = 0; r < 4; ++r) {
        size_t idx = (row0 + tb + quad * 4 + r) * 64 + n;
        xout[idx] = f2bu(b2f(xin[idx]) + acc[r]);
      }
    }
  }

  // wave-local gate write (no barrier): own 16 rows, fully coalesced
#pragma unroll
  for (int i = 0; i < 2; ++i) {
    int e = lane + i * 64;
    int rr = w * 16 + (e >> 3), c0 = (e & 7) * 8;
    *(bf16x8*)(gate_out + (row0 + t0 + rr) * 64 + c0) = *(const bf16x8*)&gt[rr][c0];
  }
}

// ---------------------------------------------------------------------------
// chain5hi (ROUND-3 PROVEN): FALLBACK path only.
// ---------------------------------------------------------------------------
__global__ __launch_bounds__(384) void chain5hi_kernel(
    const ushort_t* __restrict__ xin, ushort_t* __restrict__ xout,
    ushort_t* __restrict__ gates,
    const ushort_t* __restrict__ wt,
    const float* __restrict__ cb_all, const float* __restrict__ rb_all,
    int lbase, int write_x)
{
  __shared__ __align__(16) ushort_t xt[96][72];   // 13.5 KB
  __shared__ __align__(16) ushort_t gt[96][72];   // 13.5 KB

  const int tid = threadIdx.x;
  const int w = tid >> 6, lane = tid & 63;      // w = tile 0..5
  const int quad = lane >> 4, c16 = lane & 15;
  const int bb = blockIdx.x >> 7;
  const int sub = blockIdx.x & 127;
  const int k = sub & 31;                       // subsequence phase
  const int i0 = (sub >> 5) << 6;               // segment base (0,64,128,192)
  const size_t row0 = (size_t)bb * NT;

  // ---- stage: LDS row r <- x[(i0+r-32)*32 + k] ----
#pragma unroll
  for (int i = 0; i < 2; ++i) {
    int e = tid + i * 384;
    int r = e >> 3, c0 = (e & 7) * 8;
    int ii = i0 + r - 32;
    bf16x8 v;
    if (ii >= 0) v = *(const bf16x8*)(xin + (row0 + (size_t)ii * 32 + k) * 64 + c0);
    else { bf16x8 z = {0, 0, 0, 0, 0, 0, 0, 0}; v = z; }
    *(bf16x8*)&xt[r][c0] = v;
  }
  __syncthreads();

  for (int j = 0; j < 5; ++j) {
    const int l = lbase + j;
    const int d = 1 << j;                        // dilation in subseq space
    const ushort_t* wcat = wt + OFF_WCAT + l * 16384;
    const ushort_t* rww  = wt + OFF_RW + l * 4096;
    const float* cb = cb_all + l * 128;
    const float* rb = rb_all + l * 64;

    // ---- phase A ----
    bf16x8 af[4];
    {
      int lr = w * 16 + c16;
#pragma unroll
      for (int kk = 0; kk < 4; ++kk) {
        int rr = (kk < 2) ? lr - d : lr;
        int ch = (kk & 1) * 32 + quad * 8;
        if (rr >= 0) af[kk] = *(const bf16x8*)&xt[rr][ch];
        else { bf16x8 z = {0, 0, 0, 0, 0, 0, 0, 0}; af[kk] = z; }
      }
    }
    __syncthreads();

    // ---- phase B ----
    {
      f32x4 acc[8];
#pragma unroll
      for (int q = 0; q < 4; ++q) {
        float ba = cb[q * 16 + c16], bs = cb[q * 16 + c16 + 64];
        f32x4 va = {ba, ba, ba, ba}, vb = {bs, bs, bs, bs};
        acc[q] = va; acc[4 + q] = vb;
      }
#pragma unroll
      for (int kk = 0; kk < 4; ++kk) {
        const ushort_t* wp = wcat + kk * 4096 + c16 * 32 + quad * 8;
#pragma unroll
        for (int q = 0; q < 4; ++q) {
          acc[q]     = MFMA(af[kk], *(const bf16x8*)(wp + q * 512), acc[q]);
          acc[4 + q] = MFMA(af[kk], *(const bf16x8*)(wp + q * 512 + 2048), acc[4 + q]);
        }
      }
#pragma unroll
      for (int q = 0; q < 4; ++q)
#pragma unroll
        for (int r = 0; r < 4; ++r) {
          float e2 = __expf(2.f * acc[q][r]);
          float th = (e2 - 1.f) / (e2 + 1.f);
          float sg = 1.f / (1.f + __expf(-acc[4 + q][r]));
          gt[w * 16 + quad * 4 + r][q * 16 + c16] = f2bu(th * sg);
        }

      if (write_x || j < 4) {
        bf16x8 gf0 = *(const bf16x8*)&gt[w * 16 + c16][quad * 8];
        bf16x8 gf1 = *(const bf16x8*)&gt[w * 16 + c16][32 + quad * 8];

        f32x4 acc2[4];
#pragma unroll
        for (int q = 0; q < 4; ++q) {
          float bv = rb[q * 16 + c16];
          f32x4 z = {bv, bv, bv, bv};
          acc2[q] = z;
        }
        const ushort_t* wp2 = rww + c16 * 32 + quad * 8;
#pragma unroll
        for (int q = 0; q < 4; ++q)
          acc2[q] = MFMA(gf0, *(const bf16x8*)(wp2 + q * 512), acc2[q]);
#pragma unroll
        for (int q = 0; q < 4; ++q)
          acc2[q] = MFMA(gf1, *(const bf16x8*)(wp2 + q * 512 + 2048), acc2[q]);
#pragma unroll
        for (int q = 0; q < 4; ++q) {
          int n = q * 16 + c16;
#pragma unroll
          for (int r = 0; r < 4; ++r) {
            int rowi = w * 16 + quad * 4 + r;
            xt[rowi][n] = f2bu(b2f(xt[rowi][n]) + acc2[q][r]);
          }
        }
      }
    }
    __syncthreads();

    // ---- phase E: coop gate write (own 64 subseq rows, decimated addr) ----
    {
      ushort_t* gslot = gates + (size_t)j * G_ELEMS;
      int e = tid;
      {
        int r = e >> 3, c0 = (e & 7) * 8;
        *(bf16x8*)(gslot + (row0 + (size_t)(i0 + r) * 32 + k) * 64 + c0) =
            *(const bf16x8*)&gt[32 + r][c0];
      }
      e = tid + 384;
      if (e < 512) {
        int r = e >> 3, c0 = (e & 7) * 8;
        *(bf16x8*)(gslot + (row0 + (size_t)(i0 + r) * 32 + k) * 64 + c0) =
            *(const bf16x8*)&gt[32 + r][c0];
      }
    }
  }
  __syncthreads();

  // ---- write back x rows (i0 .. i0+63)*32 + k ----
  if (write_x) {
    int e = tid;
    {
      int r = e >> 3, c0 = (e & 7) * 8;
      *(bf16x8*)(xout + (row0 + (size_t)(i0 + r) * 32 + k) * 64 + c0) =
          *(const bf16x8*)&xt[32 + r][c0];
    }
    e = tid + 384;
    if (e < 512) {
      int r = e >> 3, c0 = (e & 7) * 8;
      *(bf16x8*)(xout + (row0 + (size_t)(i0 + r) * 32 + k) * 64 + c0) =
          *(const bf16x8*)&xt[32 + r][c0];
    }
  }
}

// ---------------------------------------------------------------------------
// FUSED skip-over-all-30-layers + head (ROUND-5/6/9 PROVEN FORM):
// K=1920 GEMM with single-barrier double-buffered weight staging + depth-1
// gate prefetch, fp32 accumulation, then the round-1-proven head phases.
// ---------------------------------------------------------------------------
__global__ __launch_bounds__(256) void skip30_head_kernel(
    const ushort_t* __restrict__ gates,   // 30 slots
    const ushort_t* __restrict__ wt,
    const float* __restrict__ sbtot,      // 256 totals (all 30 layers)
    const float* __restrict__ b0, const float* __restrict__ b1,
    const int* __restrict__ wf, const int* __restrict__ lens,
    float* __restrict__ loss)
{
  __shared__ __align__(16) ushort_t wbuf[2][8192];    // 32 KB (double buffer)
  __shared__ __align__(16) ushort_t tile[64][264];    // 33.8 KB
  const int tid = threadIdx.x;
  const int w = tid >> 6, lane = tid & 63;
  const int quad = lane >> 4, c16 = lane & 15;
  const int bb = blockIdx.x >> 7;
  const int t0 = (blockIdx.x & 127) << 6;
  const int tb = t0 + w * 16;
  const size_t row0 = (size_t)bb * NT;
  const int mylen = lens[bb];
  const ushort_t* swg = wt + OFF_SWG;

  // ---- phase 1: skip = sum over 60 K-chunks (fp32 regs) ----
  f32x4 acc[16];
#pragma unroll
  for (int nt = 0; nt < 16; ++nt) { f32x4 z = {0.f, 0.f, 0.f, 0.f}; acc[nt] = z; }

  const size_t arow = (row0 + tb + c16) * 64;
  bf16x8 wreg[4];
#pragma unroll
  for (int i = 0; i < 4; ++i)
    wreg[i] = ((const bf16x8*)swg)[tid + i * 256];
  bf16x8 af = *(const bf16x8*)(gates + arow + quad * 8);
  int cur = 0;

  for (int kk = 0; kk < 60; ++kk) {
    // commit staged regs for chunk kk
#pragma unroll
    for (int i = 0; i < 4; ++i)
      ((bf16x8*)wbuf[cur])[tid + i * 256] = wreg[i];
    // prefetch chunk kk+1 (weights + gate frag)
    int kn = (kk + 1 < 60) ? kk + 1 : 59;
#pragma unroll
    for (int i = 0; i < 4; ++i)
      wreg[i] = ((const bf16x8*)(swg + (size_t)kn * 8192))[tid + i * 256];
    bf16x8 afn = *(const bf16x8*)(gates + (size_t)(kn >> 1) * G_ELEMS + arow +
                                  (kn & 1) * 32 + quad * 8);
    __syncthreads();   // wbuf[cur] fully written (single barrier per iter)
    const ushort_t* wp = wbuf[cur] + c16 * 32 + quad * 8;
#pragma unroll
    for (int nt = 0; nt < 16; ++nt)
      acc[nt] = MFMA(af, *(const bf16x8*)(wp + nt * 512), acc[nt]);
    af = afn; cur ^= 1;
  }

  // ---- phase 2: skip + total bias -> tile (bf16, wave-private rows) ----
#pragma unroll
  for (int nt = 0; nt < 16; ++nt) {
    int n = nt * 16 + c16;
    float sbn = sbtot[n];
#pragma unroll
    for (int r = 0; r < 4; ++r)
      tile[w * 16 + quad * 4 + r][n] = f2bu(acc[nt][r] + sbn);
  }

  // ---- phase 3: hid = relu(skip @ w0 + b0) -> tile in place ----
  const ushort_t* w0T = wt + OFF_W0;
  f32x4 accA[16];
#pragma unroll
  for (int nt = 0; nt < 16; ++nt) {
    float bv = b0[nt * 16 + c16];
    f32x4 z = {bv, bv, bv, bv};
    accA[nt] = z;
  }
  for (int kk = 0; kk < 8; ++kk) {
#pragma unroll
    for (int i = 0; i < 4; ++i)
      ((bf16x8*)wbuf[0])[tid + i * 256] = ((const bf16x8*)(w0T + kk * 8192))[tid + i * 256];
    __syncthreads();
    bf16x8 hf = *(const bf16x8*)&tile[w * 16 + c16][kk * 32 + quad * 8];
    const ushort_t* wp = wbuf[0] + c16 * 32 + quad * 8;
#pragma unroll
    for (int nt = 0; nt < 16; ++nt)
      accA[nt] = MFMA(hf, *(const bf16x8*)(wp + nt * 512), accA[nt]);
    __syncthreads();
  }
#pragma unroll
  for (int nt = 0; nt < 16; ++nt)
#pragma unroll
    for (int r = 0; r < 4; ++r)
      tile[w * 16 + quad * 4 + r][nt * 16 + c16] = f2bu(fmaxf(accA[nt][r], 0.f));

  // ---- phase 4: logits = hid @ w1 + b1 ----
  const ushort_t* w1T = wt + OFF_W1;
  f32x4 acc2[16];
#pragma unroll
  for (int nt = 0; nt < 16; ++nt) {
    float bv = b1[nt * 16 + c16];
    f32x4 z = {bv, bv, bv, bv};
    acc2[nt] = z;
  }
  for (int kk = 0; kk < 8; ++kk) {
#pragma unroll
    for (int i = 0; i < 4; ++i)
      ((bf16x8*)wbuf[0])[tid + i * 256] = ((const bf16x8*)(w1T + kk * 8192))[tid + i * 256];
    __syncthreads();
    bf16x8 hf = *(const bf16x8*)&tile[w * 16 + c16][kk * 32 + quad * 8];
    const ushort_t* wp = wbuf[0] + c16 * 32 + quad * 8;
#pragma unroll
    for (int nt = 0; nt < 16; ++nt)
      acc2[nt] = MFMA(hf, *(const bf16x8*)(wp + nt * 512), acc2[nt]);
    __syncthreads();
  }

  int lblv[4];
#pragma unroll
  for (int r = 0; r < 4; ++r)
    lblv[r] = wf[row0 + tb + quad * 4 + r];

  // ---- phase 5: two-pass log-softmax + masked CE ----
  float local = 0.f;
#pragma unroll
  for (int r = 0; r < 4; ++r) {
    float m = -1e30f, tv = -1e30f;
#pragma unroll
    for (int nt = 0; nt < 16; ++nt) {
      float v = acc2[nt][r];
      m = fmaxf(m, v);
      if (lblv[r] == nt * 16 + c16) tv = v;
    }
#pragma unroll
    for (int dd = 1; dd < 16; dd <<= 1) m = fmaxf(m, __shfl_xor(m, dd));
    float s = 0.f;
#pragma unroll
    for (int nt = 0; nt < 16; ++nt) s += __expf(acc2[nt][r] - m);
#pragma unroll
    for (int dd = 1; dd < 16; dd <<= 1) {
      s += __shfl_xor(s, dd);
      tv = fmaxf(tv, __shfl_xor(tv, dd));
    }
    int t = tb + quad * 4 + r;
    if (c16 == 0 && t < mylen) local += (m + __logf(s)) - tv;
  }
#pragma unroll
  for (int dd = 1; dd < 64; dd <<= 1) local += __shfl_xor(local, dd);
  if (lane == 0 && local != 0.f) atomicAdd(loss, local);
}

// ---------------------------------------------------------------------------
// Skip-group GEMM (ROUND-3 PROVEN). FALLBACK (small workspace) ONLY.
// ---------------------------------------------------------------------------
__global__ __launch_bounds__(256) void skip_kernel(
    ushort_t* __restrict__ skip, const ushort_t* __restrict__ gates,
    const ushort_t* __restrict__ swg, const float* __restrict__ sbg,
    int first)
{
  __shared__ __align__(16) ushort_t wbuf[8192];   // 16 KB chunk
  const int tid = threadIdx.x;
  const int w = tid >> 6, lane = tid & 63;
  const int quad = lane >> 4, c16 = lane & 15;
  const int bb = blockIdx.x >> 7;
  const int t0 = (blockIdx.x & 127) << 6;
  const int tb = t0 + w * 16;
  const size_t row0 = (size_t)bb * NT;

  f32x4 acc[16];
#pragma unroll
  for (int nt = 0; nt < 16; ++nt) { f32x4 z = {0.f, 0.f, 0.f, 0.f}; acc[nt] = z; }

  const size_t arow = (row0 + tb + c16) * 64;
  for (int kk = 0; kk < 10; ++kk) {
#pragma unroll
    for (int i = 0; i < 4; ++i)
      ((bf16x8*)wbuf)[tid + i * 256] = ((const bf16x8*)(swg + kk * 8192))[tid + i * 256];
    __syncthreads();

    int slot = kk >> 1;
    bf16x8 af = *(const bf16x8*)(gates + (size_t)slot * G_ELEMS + arow +
                                 (kk & 1) * 32 + quad * 8);
    const ushort_t* wp = wbuf + c16 * 32 + quad * 8;
#pragma unroll
    for (int nt = 0; nt < 16; ++nt)
      acc[nt] = MFMA(af, *(const bf16x8*)(wp + nt * 512), acc[nt]);
    __syncthreads();
  }

#pragma unroll
  for (int nt = 0; nt < 16; ++nt) {
    int n = nt * 16 + c16;
    float sbn = sbg[n];
#pragma unroll
    for (int r = 0; r < 4; ++r) {
      size_t idx = (row0 + tb + quad * 4 + r) * 256 + n;
      float old = first ? 0.f : b2f(skip[idx]);
      skip[idx] = f2bu(old + acc[nt][r] + sbn);
    }
  }
}

// ---------------------------------------------------------------------------
// Head from materialized skip (ROUND-1 PROVEN). FALLBACK ONLY.
// ---------------------------------------------------------------------------
__global__ __launch_bounds__(256) void head_kernel(
    const ushort_t* __restrict__ skip,
    const ushort_t* __restrict__ w0T, const float* __restrict__ b0,
    const ushort_t* __restrict__ w1T, const float* __restrict__ b1,
    const int* __restrict__ wf, const int* __restrict__ lens,
    float* __restrict__ loss)
{
  __shared__ __align__(16) ushort_t wbuf[8192];       // 16 KB chunk
  __shared__ __align__(16) ushort_t tile[64][264];    // 33.8 KB
  const int tid = threadIdx.x;
  const int w = tid >> 6, lane = tid & 63;
  const int quad = lane >> 4, c16 = lane & 15;
  const int bb = blockIdx.x >> 7;
  const int t0 = (blockIdx.x & 127) << 6;
  const int tb = t0 + w * 16;
  const size_t row0 = (size_t)bb * NT;
  const int mylen = lens[bb];

#pragma unroll
  for (int i = 0; i < 8; ++i) {
    int e = lane + i * 64;                  // 0..511
    int r = e >> 5, c0 = (e & 31) * 8;
    *(bf16x8*)&tile[w * 16 + r][c0] =
        *(const bf16x8*)(skip + (row0 + t0 + w * 16 + r) * 256 + c0);
  }

  f32x4 accA[16];
#pragma unroll
  for (int nt = 0; nt < 16; ++nt) {
    float bv = b0[nt * 16 + c16];
    f32x4 z = {bv, bv, bv, bv};
    accA[nt] = z;
  }
  for (int kk = 0; kk < 8; ++kk) {
#pragma unroll
    for (int i = 0; i < 4; ++i)
      ((bf16x8*)wbuf)[tid + i * 256] = ((const bf16x8*)(w0T + kk * 8192))[tid + i * 256];
    __syncthreads();
    bf16x8 af = *(const bf16x8*)&tile[w * 16 + c16][kk * 32 + quad * 8];
    const ushort_t* wp = wbuf + c16 * 32 + quad * 8;
#pragma unroll
    for (int nt = 0; nt < 16; ++nt)
      accA[nt] = MFMA(af, *(const bf16x8*)(wp + nt * 512), accA[nt]);
    __syncthreads();
  }
#pragma unroll
  for (int nt = 0; nt < 16; ++nt)
#pragma unroll
    for (int r = 0; r < 4; ++r)
      tile[w * 16 + quad * 4 + r][nt * 16 + c16] = f2bu(fmaxf(accA[nt][r], 0.f));

  f32x4 acc2[16];
#pragma unroll
  for (int nt = 0; nt < 16; ++nt) {
    float bv = b1[nt * 16 + c16];
    f32x4 z = {bv, bv, bv, bv};
    acc2[nt] = z;
  }
  for (int kk = 0; kk < 8; ++kk) {
#pragma unroll
    for (int i = 0; i < 4; ++i)
      ((bf16x8*)wbuf)[tid + i * 256] = ((const bf16x8*)(w1T + kk * 8192))[tid + i * 256];
    __syncthreads();
    bf16x8 hf = *(const bf16x8*)&tile[w * 16 + c16][kk * 32 + quad * 8];
    const ushort_t* wp = wbuf + c16 * 32 + quad * 8;
#pragma unroll
    for (int nt = 0; nt < 16; ++nt)
      acc2[nt] = MFMA(hf, *(const bf16x8*)(wp + nt * 512), acc2[nt]);
    __syncthreads();
  }

  int lblv[4];
#pragma unroll
  for (int r = 0; r < 4; ++r)
    lblv[r] = wf[row0 + tb + quad * 4 + r];

  float local = 0.f;
#pragma unroll
  for (int r = 0; r < 4; ++r) {
    float m = -1e30f, tv = -1e30f;
#pragma unroll
    for (int nt = 0; nt < 16; ++nt) {
      float v = acc2[nt][r];
      m = fmaxf(m, v);
      if (lblv[r] == nt * 16 + c16) tv = v;
    }
#pragma unroll
    for (int dd = 1; dd < 16; dd <<= 1) m = fmaxf(m, __shfl_xor(m, dd));
    float s = 0.f;
#pragma unroll
    for (int nt = 0; nt < 16; ++nt) s += __expf(acc2[nt][r] - m);
#pragma unroll
    for (int dd = 1; dd < 16; dd <<= 1) {
      s += __shfl_xor(s, dd);
      tv = fmaxf(tv, __shfl_xor(tv, dd));
    }
    int t = tb + quad * 4 + r;
    if (c16 == 0 && t < mylen) local += (m + __logf(s)) - tv;
  }
#pragma unroll
  for (int dd = 1; dd < 64; dd <<= 1) local += __shfl_xor(local, dd);
  if (lane == 0 && local != 0.f) atomicAdd(loss, local);
}

__global__ void finalize_kernel(const int* __restrict__ lens,
                                float* __restrict__ out)
{
  if (threadIdx.x == 0) {
    float den = 0.f;
    for (int b = 0; b < NB; ++b) {
      int l = lens[b];
      if (l > NT) l = NT;
      den += (float)l;
    }
    out[0] = out[0] / fmaxf(den, 1.f);
  }
}

// ---------------------------------------------------------------------------
extern "C" void kernel_launch(void* const* d_in, const int* in_sizes, int n_in,
                              void* d_out, int out_size, void* d_ws, size_t ws_size,
                              hipStream_t stream) {
  const int*   wf     = (const int*)d_in[0];
  const int*   lens   = (const int*)d_in[1];
  const float* embed  = (const float*)d_in[2];
  const float* conv_w = (const float*)d_in[3];
  const float* conv_b = (const float*)d_in[4];
  const float* res_w  = (const float*)d_in[5];
  const float* res_b  = (const float*)d_in[6];
  const float* skip_w = (const float*)d_in[7];
  const float* skip_b = (const float*)d_in[8];
  const float* w0     = (const float*)d_in[9];
  const float* b0     = (const float*)d_in[10];
  const float* w1     = (const float*)d_in[11];
  const float* b1     = (const float*)d_in[12];

  float* out = (float*)d_out;
  if (ws_size < WS_SMALL) {
    sentinel_kernel<<<1, 64, 0, stream>>>(out);
    return;
  }
  const bool big = (ws_size >= WS_BIG);

  static const int dil[NL] = {1, 2, 4, 8, 16, 32, 64, 128, 256, 512,
                              1, 2, 4, 8, 16, 32, 64, 128, 256, 512,
                              1, 2, 4, 8, 16, 32, 64, 128, 256, 512};

  if (big) {
    // layout: x0, x1, gates[30], wt, sbg[1792]
    ushort_t* x0    = (ushort_t*)d_ws;
    ushort_t* x1    = x0 + X_ELEMS;
    ushort_t* gates = x1 + X_ELEMS;                   // 30 x 4 MB
    ushort_t* wt    = gates + 30 * (size_t)G_ELEMS;
    float*    sbg   = (float*)(wt + TOTAL_W);

    prep_kernel<<<(N_PREP + 255) / 256, 256, 0, stream>>>(
        conv_w, res_w, skip_w, w0, w1, skip_b, wt, sbg, out);

    const ushort_t* xin = x0;
    ushort_t* xout = x1;
    for (int blk = 0; blk < 3; ++blk) {
      const int l0 = blk * 10;
      // low-dilation half: proven chain (writes gate slots l0..l0+4)
      chain5_kernel<<<512, 384, 0, stream>>>(
          xin, xout, gates + (size_t)l0 * G_ELEMS,
          wt, conv_b, res_b, l0, wf, blk == 0 ? embed : nullptr);
      { const ushort_t* t = xout; xout = (ushort_t*)xin; xin = t; }
      // high-dilation half: proven per-layer kernels, dedicated gate slots
      for (int l = l0 + 5; l < l0 + 10; ++l) {
        layer_kernel<<<512, 256, 0, stream>>>(
            xin, xout, gates + (size_t)l * G_ELEMS,
            wt + OFF_WCAT + l * 16384, conv_b + l * 128,
            wt + OFF_RW + l * 4096,    res_b + l * 64,
            dil[l], l < NL - 1 ? 1 : 0);
        { const ushort_t* t = xout; xout = (ushort_t*)xin; xin = t; }
      }
    }

    skip30_head_kernel<<<512, 256, 0, stream>>>(
        gates, wt, sbg + 1536, b0, b1, wf, lens, out);
    finalize_kernel<<<1, 64, 0, stream>>>(lens, out);
  } else {
    // ROUND-3 PROVEN fallback: x0, x1, skip, gates[5], wt, sbg
    ushort_t* x0    = (ushort_t*)d_ws;
    ushort_t* x1    = x0 + X_ELEMS;
    ushort_t* skip  = x1 + X_ELEMS;
    ushort_t* gates = skip + SK_ELEMS;
    ushort_t* wt    = gates + 5 * (size_t)G_ELEMS;
    float*    sbg   = (float*)(wt + TOTAL_W);

    prep_kernel<<<(N_PREP + 255) / 256, 256, 0, stream>>>(
        conv_w, res_w, skip_w, w0, w1, skip_b, wt, sbg, out);
    embed_kernel<<<512, 256, 0, stream>>>(wf, embed, x0);

    const ushort_t* xin = x0;
    ushort_t* xout = x1;
    for (int blk = 0; blk < 3; ++blk) {
      const int l0 = blk * 10;
      chain5_kernel<<<512, 384, 0, stream>>>(
          xin, xout, gates, wt, conv_b, res_b, l0, wf, nullptr);
      { const ushort_t* t = xout; xout = (ushort_t*)xin; xin = t; }
      skip_kernel<<<512, 256, 0, stream>>>(
          skip, gates, wt + OFF_SWG + (size_t)(2 * blk) * 81920,
          sbg + (size_t)(2 * blk) * 256, blk == 0 ? 1 : 0);
      chain5hi_kernel<<<512, 384, 0, stream>>>(
          xin, xout, gates, wt, conv_b, res_b, l0 + 5, blk < 2 ? 1 : 0);
      { const ushort_t* t = xout; xout = (ushort_t*)xin; xin = t; }
      skip_kernel<<<512, 256, 0, stream>>>(
          skip, gates, wt + OFF_SWG + (size_t)(2 * blk + 1) * 81920,
          sbg + (size_t)(2 * blk + 1) * 256, 0);
    }

    head_kernel<<<512, 256, 0, stream>>>(
        skip, wt + OFF_W0, b0, wt + OFF_W1, b1, wf, lens, out);
    finalize_kernel<<<1, 64, 0, stream>>>(lens, out);
  }
}